// Round 4
// baseline (155.214 us; speedup 1.0000x reference)
//
#include <hip/hip_runtime.h>
#include <hip/hip_bf16.h>

#define B_ROWS 4096
#define TWOB   8192
#define DIM    256
#define INV_T  14.285714285714286f  // 1/0.07

#define BM 128
#define BN 128
#define NSTRIP 16
#define CT_PER_STRIP 4    // (8192/128)/NSTRIP
#define NIT (CT_PER_STRIP * 8)   // flattened (ct,kt) iterations

typedef __bf16 bf16x8 __attribute__((ext_vector_type(8)));
typedef float  f32x4  __attribute__((ext_vector_type(4)));

// ---------------- kernel 1: row L2-normalize, fp32 -> bf16 ----------------
// Also zeroes the finalize accumulators (ws is re-poisoned 0xAA before every launch).
__global__ __launch_bounds__(256) void normalize_k(const float* __restrict__ zi,
                                                   const float* __restrict__ zj,
                                                   unsigned short* __restrict__ zn,
                                                   float* __restrict__ loss_acc,
                                                   unsigned int* __restrict__ counter) {
    if (blockIdx.x == 0 && threadIdx.x == 0) {
        loss_acc[0] = 0.0f;
        counter[0]  = 0u;
    }
    int wave = threadIdx.x >> 6;
    int lane = threadIdx.x & 63;
    int row  = blockIdx.x * 4 + wave;             // 2048 blocks * 4 waves = 8192 rows
    const float* src = (row < B_ROWS) ? (zi + (size_t)row * DIM)
                                      : (zj + (size_t)(row - B_ROWS) * DIM);
    float4 v = reinterpret_cast<const float4*>(src)[lane];   // 64 lanes * 4 = 256
    float ss = v.x * v.x + v.y * v.y + v.z * v.z + v.w * v.w;
#pragma unroll
    for (int off = 32; off >= 1; off >>= 1) ss += __shfl_xor(ss, off);
    float norm = sqrtf(ss);
    norm = fmaxf(norm, 1e-8f);                    // COS_EPS
    float inv = 1.0f / norm;
    ushort4 o;
    o.x = __builtin_bit_cast(unsigned short, __float2bfloat16(v.x * inv));
    o.y = __builtin_bit_cast(unsigned short, __float2bfloat16(v.y * inv));
    o.z = __builtin_bit_cast(unsigned short, __float2bfloat16(v.z * inv));
    o.w = __builtin_bit_cast(unsigned short, __float2bfloat16(v.w * inv));
    reinterpret_cast<ushort4*>(zn)[(size_t)row * 64 + lane] = o;
}

// ---------------- kernel 2: flash NT-Xent main ----------------
// Grid: (64 row-tiles, NSTRIP col strips) = 1024 blocks, 4 waves (2x2) each.
// Flattened (ct,kt) pipeline with double-buffered LDS: stage(it+1) is issued
// right after the single per-iteration barrier, so the barrier's vmcnt(0)
// drain at it+1 lands after a full compute phase has hidden the L2 latency.
// (R3's stage->barrier->compute exposed ~300 cyc/iter; at the ~2 blocks/CU
// residency forced by 108 VGPR + 64 AGPR, that serialized the whole loop.)
__global__ __launch_bounds__(256) void ntxent_main(const unsigned short* __restrict__ znu,
                                                   float* __restrict__ pos,
                                                   float* __restrict__ strip_sums) {
    const __bf16* zn = (const __bf16*)znu;
    __shared__ __attribute__((aligned(16))) __bf16 As[2][BM * 32];   // 2 x 8 KB, XOR-swizzled 16B chunks
    __shared__ __attribute__((aligned(16))) __bf16 Bs[2][BN * 32];   // 2 x 8 KB
    __shared__ float rowsumL[2][BM];                                 // per-wc halves

    const int tid  = threadIdx.x;
    const int wave = tid >> 6;
    const int lane = tid & 63;
    const int wr = wave >> 1, wc = wave & 1;
    const int quad = lane >> 4, lc = lane & 15;
    const int rt    = blockIdx.x;        // row-tile 0..63
    const int strip = blockIdx.y;        // 0..NSTRIP-1
    const int row0  = rt * BM;
    const int posTile = (rt + 32) & 63;  // col-tile holding (row+4096) mod 8192

    // staging: per-lane global element offsets for this wave's two 1KB chunks per stage.
    // chunk c = j*64+lane -> (m=c>>2, kc_lds=c&3); source kc_g = kc_lds ^ sw(m)  (involution)
    int stg_off[2];
#pragma unroll
    for (int t = 0; t < 2; ++t) {
        int c  = (wave * 2 + t) * 64 + lane;
        int m  = c >> 2;
        int kc = (c & 3) ^ ((m & 3) ^ ((m >> 2) & 3));
        stg_off[t] = m * DIM + kc * 8;
    }

    // fragment-read byte offsets within one 8KB buffer (swizzle depends only on m&15 == lc)
    const int sw    = (lc & 3) ^ ((lc >> 2) & 3);
    const int aBase = (wr * 64 + lc) * 64 + ((quad ^ sw) * 16);
    const int bBase = (wc * 64 + lc) * 64 + ((quad ^ sw) * 16);

    // stage iteration `it` into buffer `buf`
    auto stage = [&](int it, int buf) {
        const int kt   = it & 7;
        const int ct   = it >> 3;
        const int col0 = (strip * CT_PER_STRIP + ct) * BN;
        const int k0   = kt * 32;
#pragma unroll
        for (int t = 0; t < 2; ++t) {
            const int j = wave * 2 + t;
            const __bf16* ga = zn + row0 * DIM + k0 + stg_off[t];
            const __bf16* gb = zn + col0 * DIM + k0 + stg_off[t];
            __builtin_amdgcn_global_load_lds(
                (const __attribute__((address_space(1))) void*)ga,
                (__attribute__((address_space(3))) void*)((char*)As + buf * 8192 + j * 1024), 16, 0, 0);
            __builtin_amdgcn_global_load_lds(
                (const __attribute__((address_space(1))) void*)gb,
                (__attribute__((address_space(3))) void*)((char*)Bs + buf * 8192 + j * 1024), 16, 0, 0);
        }
    };

    f32x4 acc[4][4];
    float rsum[4][4];
#pragma unroll
    for (int mi = 0; mi < 4; ++mi)
#pragma unroll
        for (int r = 0; r < 4; ++r) rsum[mi][r] = 0.0f;

    stage(0, 0);

    for (int it = 0; it < NIT; ++it) {
        const int buf = it & 1;
        if ((it & 7) == 0) {
#pragma unroll
            for (int mi = 0; mi < 4; ++mi)
#pragma unroll
                for (int ni = 0; ni < 4; ++ni) acc[mi][ni] = f32x4{0.f, 0.f, 0.f, 0.f};
        }

        // one barrier per iteration: drains stage(it)'s vmcnt (covered by the
        // previous iteration's compute) and guards LDS reuse of buf^1.
        __syncthreads();
        if (it + 1 < NIT) stage(it + 1, buf ^ 1);

        bf16x8 af[4], bfr[4];
#pragma unroll
        for (int mi = 0; mi < 4; ++mi)
            af[mi] = *(const bf16x8*)((const char*)As + buf * 8192 + aBase + mi * 1024);
#pragma unroll
        for (int ni = 0; ni < 4; ++ni)
            bfr[ni] = *(const bf16x8*)((const char*)Bs + buf * 8192 + bBase + ni * 1024);
#pragma unroll
        for (int mi = 0; mi < 4; ++mi)
#pragma unroll
            for (int ni = 0; ni < 4; ++ni)
                acc[mi][ni] = __builtin_amdgcn_mfma_f32_16x16x32_bf16(
                    af[mi], bfr[ni], acc[mi][ni], 0, 0, 0);

        if ((it & 7) == 7) {
            // epilogue for ct = it>>3: exp + running row sums
            // (C/D layout: row = quad*4+reg, col = lc)
            const int colTile = strip * CT_PER_STRIP + (it >> 3);
            const int col0 = colTile * BN;
            const bool special = (colTile == rt) || (colTile == posTile);
#pragma unroll
            for (int mi = 0; mi < 4; ++mi) {
#pragma unroll
                for (int ni = 0; ni < 4; ++ni) {
                    f32x4 a = acc[mi][ni];
#pragma unroll
                    for (int r = 0; r < 4; ++r) {
                        float logit = a[r] * INV_T;
                        float e = __expf(logit);
                        if (special) {
                            int gr = row0 + wr * 64 + mi * 16 + quad * 4 + r;
                            int gc = col0 + wc * 64 + ni * 16 + lc;
                            if (gc == ((gr + B_ROWS) & (TWOB - 1))) pos[gr] = logit;
                            if (gr == gc) e = 0.0f;    // diagonal mask
                        }
                        rsum[mi][r] += e;
                    }
                }
            }
        }
    }

    // cross-lane: sum the 16 columns (low 4 lane bits) holding each row
#pragma unroll
    for (int mi = 0; mi < 4; ++mi) {
#pragma unroll
        for (int r = 0; r < 4; ++r) {
            float v = rsum[mi][r];
            v += __shfl_xor(v, 1);
            v += __shfl_xor(v, 2);
            v += __shfl_xor(v, 4);
            v += __shfl_xor(v, 8);
            if (lc == 0) rowsumL[wc][wr * 64 + mi * 16 + quad * 4 + r] = v;
        }
    }
    __syncthreads();
    if (tid < BM)
        strip_sums[(size_t)strip * TWOB + row0 + tid] = rowsumL[0][tid] + rowsumL[1][tid];
}

// ---------------- kernel 3: loss = mean(log(sumexp) - pos) ----------------
// 32 blocks x 256 threads, one row per thread. Device-scope atomic accumulation;
// last block to finish writes the mean. Accumulators zeroed by normalize_k.
__global__ __launch_bounds__(256) void finalize_k(const float* __restrict__ strip_sums,
                                                  const float* __restrict__ pos,
                                                  float* __restrict__ loss_acc,
                                                  unsigned int* __restrict__ counter,
                                                  float* __restrict__ out) {
    __shared__ float wsums[4];
    const int tid = threadIdx.x;
    const int r   = blockIdx.x * 256 + tid;
    float s = 0.0f;
#pragma unroll
    for (int st = 0; st < NSTRIP; ++st) s += strip_sums[(size_t)st * TWOB + r];
    float local = logf(s) - pos[r];
#pragma unroll
    for (int off = 32; off >= 1; off >>= 1) local += __shfl_xor(local, off);
    if ((tid & 63) == 0) wsums[tid >> 6] = local;
    __syncthreads();
    if (tid == 0) {
        float bsum = wsums[0] + wsums[1] + wsums[2] + wsums[3];
        atomicAdd(loss_acc, bsum);
        __threadfence();                              // order loss add before counter add
        unsigned int done = atomicAdd(counter, 1u);
        if (done == gridDim.x - 1) {
            float total = atomicAdd(loss_acc, 0.0f);  // device-scope atomic read
            out[0] = total / (float)TWOB;
        }
    }
}

extern "C" void kernel_launch(void* const* d_in, const int* in_sizes, int n_in,
                              void* d_out, int out_size, void* d_ws, size_t ws_size,
                              hipStream_t stream) {
    const float* zi = (const float*)d_in[0];
    const float* zj = (const float*)d_in[1];
    // ws layout: zn (4 MB) | pos (32 KB) | strip_sums (512 KB) | loss_acc | counter
    unsigned short* zn = (unsigned short*)d_ws;
    float* pos        = (float*)((char*)d_ws + (size_t)TWOB * DIM * 2);
    float* strip_sums = pos + TWOB;
    float* loss_acc   = strip_sums + (size_t)NSTRIP * TWOB;
    unsigned int* counter = (unsigned int*)(loss_acc + 1);
    float* out = (float*)d_out;

    normalize_k<<<dim3(TWOB / 4), 256, 0, stream>>>(zi, zj, zn, loss_acc, counter);
    ntxent_main<<<dim3(64, NSTRIP), 256, 0, stream>>>(zn, pos, strip_sums);
    finalize_k<<<dim3(TWOB / 256), 256, 0, stream>>>(strip_sums, pos, loss_acc, counter, out);
}

// Round 5
// 107.236 us; speedup vs baseline: 1.4474x; 1.4474x over previous
//
#include <hip/hip_runtime.h>
#include <hip/hip_bf16.h>

#define B_ROWS 4096
#define TWOB   8192
#define DIM    256
#define INV_T  14.285714285714286f  // 1/0.07

#define BM 128
#define BN 128
#define NSTRIP 8
#define CT_PER_STRIP 8    // (8192/128)/NSTRIP

typedef __bf16 bf16x8 __attribute__((ext_vector_type(8)));
typedef float  f32x4  __attribute__((ext_vector_type(4)));

// ---------------- kernel 1: row L2-normalize, fp32 -> bf16 ----------------
// Also zeroes the finalize accumulators (ws is re-poisoned 0xAA before every launch).
__global__ __launch_bounds__(256) void normalize_k(const float* __restrict__ zi,
                                                   const float* __restrict__ zj,
                                                   unsigned short* __restrict__ zn,
                                                   float* __restrict__ loss_acc,
                                                   unsigned int* __restrict__ counter) {
    if (blockIdx.x == 0 && threadIdx.x == 0) {
        loss_acc[0] = 0.0f;
        counter[0]  = 0u;
    }
    int wave = threadIdx.x >> 6;
    int lane = threadIdx.x & 63;
    int row  = blockIdx.x * 4 + wave;             // 2048 blocks * 4 waves = 8192 rows
    const float* src = (row < B_ROWS) ? (zi + (size_t)row * DIM)
                                      : (zj + (size_t)(row - B_ROWS) * DIM);
    float4 v = reinterpret_cast<const float4*>(src)[lane];   // 64 lanes * 4 = 256
    float ss = v.x * v.x + v.y * v.y + v.z * v.z + v.w * v.w;
#pragma unroll
    for (int off = 32; off >= 1; off >>= 1) ss += __shfl_xor(ss, off);
    float norm = sqrtf(ss);
    norm = fmaxf(norm, 1e-8f);                    // COS_EPS
    float inv = 1.0f / norm;
    ushort4 o;
    o.x = __builtin_bit_cast(unsigned short, __float2bfloat16(v.x * inv));
    o.y = __builtin_bit_cast(unsigned short, __float2bfloat16(v.y * inv));
    o.z = __builtin_bit_cast(unsigned short, __float2bfloat16(v.z * inv));
    o.w = __builtin_bit_cast(unsigned short, __float2bfloat16(v.w * inv));
    reinterpret_cast<ushort4*>(zn)[(size_t)row * 64 + lane] = o;
}

// ---------------- kernel 2: flash NT-Xent main ----------------
// Grid: (64 row-tiles, NSTRIP col strips) = 512 blocks, 4 waves (2x2) each.
// A-tile (128x256 = 64 KB) staged ONCE per block and kept LDS-resident (it
// depends only on kt, not ct — R3 re-staged it 8x). Only B ping-pongs
// (2 x 8 KB); stage(it+1) issues at the top of iter `it`, so the next
// barrier's vmcnt(0) drain waits on loads already covered by a full compute
// phase. kt loop fully unrolled -> all LDS offsets & buffer parity are
// compile-time (R4's runtime-buf lambda cost +72 VGPR and 1 block/CU).
// LDS = 64 + 16 = 80 KB exactly (rowsumL aliased onto As) -> 2 blocks/CU.
__global__ __launch_bounds__(256) void ntxent_main(const unsigned short* __restrict__ znu,
                                                   float* __restrict__ pos,
                                                   float* __restrict__ strip_sums) {
    const __bf16* zn = (const __bf16*)znu;
    __shared__ __attribute__((aligned(16))) __bf16 As[8][BM * 32];   // 8 kt-chunks x 8 KB = 64 KB
    __shared__ __attribute__((aligned(16))) __bf16 Bs[2][BN * 32];   // ping-pong, 16 KB

    const int tid  = threadIdx.x;
    const int wave = tid >> 6;
    const int lane = tid & 63;
    const int wr = wave >> 1, wc = wave & 1;
    const int quad = lane >> 4, lc = lane & 15;
    const int rt    = blockIdx.x;        // row-tile 0..63
    const int strip = blockIdx.y;        // 0..NSTRIP-1
    const int row0  = rt * BM;
    const int posTile = (rt + 32) & 63;  // col-tile holding (row+4096) mod 8192

    // staging: per-lane global element offsets for this wave's two 1KB chunks per stage.
    // chunk c = j*64+lane -> (m=c>>2, kc_lds=c&3); source kc_g = kc_lds ^ sw(m)  (involution)
    int stg_off[2];
#pragma unroll
    for (int t = 0; t < 2; ++t) {
        int c  = (wave * 2 + t) * 64 + lane;
        int m  = c >> 2;
        int kc = (c & 3) ^ ((m & 3) ^ ((m >> 2) & 3));
        stg_off[t] = m * DIM + kc * 8;
    }

    // fragment-read byte offsets within one 8KB chunk (swizzle depends only on m&15 == lc)
    const int sw    = (lc & 3) ^ ((lc >> 2) & 3);
    const int aBase = (wr * 64 + lc) * 64 + ((quad ^ sw) * 16);
    const int bBase = (wc * 64 + lc) * 64 + ((quad ^ sw) * 16);

    // ---- prologue: stage full A (8 chunks) + first B chunk ----
#pragma unroll
    for (int kt = 0; kt < 8; ++kt) {
#pragma unroll
        for (int t = 0; t < 2; ++t) {
            const int j = wave * 2 + t;
            const __bf16* ga = zn + row0 * DIM + kt * 32 + stg_off[t];
            __builtin_amdgcn_global_load_lds(
                (const __attribute__((address_space(1))) void*)ga,
                (__attribute__((address_space(3))) void*)((char*)As + kt * 8192 + j * 1024), 16, 0, 0);
        }
    }
    {
        const int col0 = strip * CT_PER_STRIP * BN;
#pragma unroll
        for (int t = 0; t < 2; ++t) {
            const int j = wave * 2 + t;
            const __bf16* gb = zn + col0 * DIM + stg_off[t];
            __builtin_amdgcn_global_load_lds(
                (const __attribute__((address_space(1))) void*)gb,
                (__attribute__((address_space(3))) void*)((char*)Bs + j * 1024), 16, 0, 0);
        }
    }

    f32x4 acc[4][4];
    float rsum[4][4];
#pragma unroll
    for (int mi = 0; mi < 4; ++mi)
#pragma unroll
        for (int r = 0; r < 4; ++r) rsum[mi][r] = 0.0f;

    for (int ct = 0; ct < CT_PER_STRIP; ++ct) {
        const int colTile = strip * CT_PER_STRIP + ct;
        const int col0 = colTile * BN;
#pragma unroll
        for (int mi = 0; mi < 4; ++mi)
#pragma unroll
            for (int ni = 0; ni < 4; ++ni) acc[mi][ni] = f32x4{0.f, 0.f, 0.f, 0.f};

#pragma unroll
        for (int kt = 0; kt < 8; ++kt) {
            // barrier: (a) drains the B stage issued one iteration ago (covered
            // by that iteration's compute), (b) guards reuse of Bs[kt+1 & 1].
            __syncthreads();

            // stage next B chunk into the other buffer
            {
                const int nct = (kt == 7) ? ct + 1 : ct;
                const int nkt = (kt + 1) & 7;
                if (nct < CT_PER_STRIP) {
                    const int ncol0 = (strip * CT_PER_STRIP + nct) * BN;
#pragma unroll
                    for (int t = 0; t < 2; ++t) {
                        const int j = wave * 2 + t;
                        const __bf16* gb = zn + ncol0 * DIM + nkt * 32 + stg_off[t];
                        __builtin_amdgcn_global_load_lds(
                            (const __attribute__((address_space(1))) void*)gb,
                            (__attribute__((address_space(3))) void*)((char*)Bs + ((kt + 1) & 1) * 8192 + j * 1024),
                            16, 0, 0);
                    }
                }
            }

            bf16x8 af[4], bfr[4];
#pragma unroll
            for (int mi = 0; mi < 4; ++mi)
                af[mi] = *(const bf16x8*)((const char*)As + kt * 8192 + aBase + mi * 1024);
#pragma unroll
            for (int ni = 0; ni < 4; ++ni)
                bfr[ni] = *(const bf16x8*)((const char*)Bs + (kt & 1) * 8192 + bBase + ni * 1024);
#pragma unroll
            for (int mi = 0; mi < 4; ++mi)
#pragma unroll
                for (int ni = 0; ni < 4; ++ni)
                    acc[mi][ni] = __builtin_amdgcn_mfma_f32_16x16x32_bf16(
                        af[mi], bfr[ni], acc[mi][ni], 0, 0, 0);
        }

        // epilogue: exp + running row sums (C/D layout: row = quad*4+reg, col = lc).
        // Runs while the B(ct+1, kt=0) stage is in flight — extra latency cover.
        const bool special = (colTile == rt) || (colTile == posTile);
#pragma unroll
        for (int mi = 0; mi < 4; ++mi) {
#pragma unroll
            for (int ni = 0; ni < 4; ++ni) {
                f32x4 a = acc[mi][ni];
#pragma unroll
                for (int r = 0; r < 4; ++r) {
                    float logit = a[r] * INV_T;
                    float e = __expf(logit);
                    if (special) {
                        int gr = row0 + wr * 64 + mi * 16 + quad * 4 + r;
                        int gc = col0 + wc * 64 + ni * 16 + lc;
                        if (gc == ((gr + B_ROWS) & (TWOB - 1))) pos[gr] = logit;
                        if (gr == gc) e = 0.0f;    // diagonal mask
                    }
                    rsum[mi][r] += e;
                }
            }
        }
    }

    // all MFMA/ds_reads of As are done; alias rowsumL onto As to stay at 80 KB
    __syncthreads();
    float* rowsumL = (float*)As;         // [2][BM]
#pragma unroll
    for (int mi = 0; mi < 4; ++mi) {
#pragma unroll
        for (int r = 0; r < 4; ++r) {
            float v = rsum[mi][r];
            v += __shfl_xor(v, 1);
            v += __shfl_xor(v, 2);
            v += __shfl_xor(v, 4);
            v += __shfl_xor(v, 8);
            if (lc == 0) rowsumL[wc * BM + wr * 64 + mi * 16 + quad * 4 + r] = v;
        }
    }
    __syncthreads();
    if (tid < BM)
        strip_sums[(size_t)strip * TWOB + row0 + tid] = rowsumL[tid] + rowsumL[BM + tid];
}

// ---------------- kernel 3: loss = mean(log(sumexp) - pos) ----------------
// 32 blocks x 256 threads, one row per thread. Device-scope atomic accumulation;
// last block to finish writes the mean. Accumulators zeroed by normalize_k.
__global__ __launch_bounds__(256) void finalize_k(const float* __restrict__ strip_sums,
                                                  const float* __restrict__ pos,
                                                  float* __restrict__ loss_acc,
                                                  unsigned int* __restrict__ counter,
                                                  float* __restrict__ out) {
    __shared__ float wsums[4];
    const int tid = threadIdx.x;
    const int r   = blockIdx.x * 256 + tid;
    float s = 0.0f;
#pragma unroll
    for (int st = 0; st < NSTRIP; ++st) s += strip_sums[(size_t)st * TWOB + r];
    float local = logf(s) - pos[r];
#pragma unroll
    for (int off = 32; off >= 1; off >>= 1) local += __shfl_xor(local, off);
    if ((tid & 63) == 0) wsums[tid >> 6] = local;
    __syncthreads();
    if (tid == 0) {
        float bsum = wsums[0] + wsums[1] + wsums[2] + wsums[3];
        atomicAdd(loss_acc, bsum);
        __threadfence();                              // order loss add before counter add
        unsigned int done = atomicAdd(counter, 1u);
        if (done == gridDim.x - 1) {
            float total = atomicAdd(loss_acc, 0.0f);  // device-scope atomic read
            out[0] = total / (float)TWOB;
        }
    }
}

extern "C" void kernel_launch(void* const* d_in, const int* in_sizes, int n_in,
                              void* d_out, int out_size, void* d_ws, size_t ws_size,
                              hipStream_t stream) {
    const float* zi = (const float*)d_in[0];
    const float* zj = (const float*)d_in[1];
    // ws layout: zn (4 MB) | pos (32 KB) | strip_sums (256 KB) | loss_acc | counter
    unsigned short* zn = (unsigned short*)d_ws;
    float* pos        = (float*)((char*)d_ws + (size_t)TWOB * DIM * 2);
    float* strip_sums = pos + TWOB;
    float* loss_acc   = strip_sums + (size_t)NSTRIP * TWOB;
    unsigned int* counter = (unsigned int*)(loss_acc + 1);
    float* out = (float*)d_out;

    normalize_k<<<dim3(TWOB / 4), 256, 0, stream>>>(zi, zj, zn, loss_acc, counter);
    ntxent_main<<<dim3(64, NSTRIP), 256, 0, stream>>>(zn, pos, strip_sums);
    finalize_k<<<dim3(TWOB / 256), 256, 0, stream>>>(strip_sums, pos, loss_acc, counter, out);
}